// Round 1
// baseline (1018.297 us; speedup 1.0000x reference)
//
#include <hip/hip_runtime.h>

#define BB 64
#define SS 2048
#define FF 256
#define CC 32

// ---------------------------------------------------------------------------
// Kernel 1: emissions[b,s,c] = sum_f X[b,s,f]*W[c,f] + bias[c]
// grid: (B*S/64) blocks x 256 threads. LDS-tiled, f32 FMA (no fp32 MFMA on CDNA4).
// ---------------------------------------------------------------------------
__global__ __launch_bounds__(256) void emis_kernel(const float* __restrict__ X,
                                                   const float* __restrict__ W,
                                                   const float* __restrict__ bias,
                                                   float* __restrict__ em) {
    __shared__ __align__(16) float xs[64 * 260];   // 64 rows, stride 260 (pad: bank spread)
    __shared__ __align__(16) float wsh[32 * 260];  // 32 rows, stride 260
    const int tid = threadIdx.x;
    const long rowbase = (long)blockIdx.x * 64;

    // Stage X tile: 64 rows x 256 f32, contiguous in global -> coalesced float4
    const float4* Xg = (const float4*)(X + rowbase * FF);
#pragma unroll
    for (int i = 0; i < 16; ++i) {
        int idx = tid + i * 256;        // 0..4095 float4 slots
        int r = idx >> 6, c4 = idx & 63;
        *(float4*)&xs[r * 260 + c4 * 4] = Xg[idx];
    }
    // Stage W: 32 x 256
    const float4* Wg = (const float4*)W;
#pragma unroll
    for (int i = 0; i < 8; ++i) {
        int idx = tid + i * 256;        // 0..2047
        int r = idx >> 6, c4 = idx & 63;
        *(float4*)&wsh[r * 260 + c4 * 4] = Wg[idx];
    }
    __syncthreads();

    const int rp = tid >> 3;            // 0..31 -> rows 2rp, 2rp+1
    const int cg = (tid & 7) * 4;       // 4 consecutive cols
    const int r0 = rp * 2, r1 = rp * 2 + 1;
    float acc0[4] = {0.f, 0.f, 0.f, 0.f};
    float acc1[4] = {0.f, 0.f, 0.f, 0.f};

#pragma unroll 4
    for (int k = 0; k < 256; k += 4) {
        float4 xa = *(const float4*)&xs[r0 * 260 + k];
        float4 xb = *(const float4*)&xs[r1 * 260 + k];
#pragma unroll
        for (int jj = 0; jj < 4; ++jj) {
            float4 w = *(const float4*)&wsh[(cg + jj) * 260 + k];
            acc0[jj] = fmaf(xa.x, w.x, acc0[jj]);
            acc0[jj] = fmaf(xa.y, w.y, acc0[jj]);
            acc0[jj] = fmaf(xa.z, w.z, acc0[jj]);
            acc0[jj] = fmaf(xa.w, w.w, acc0[jj]);
            acc1[jj] = fmaf(xb.x, w.x, acc1[jj]);
            acc1[jj] = fmaf(xb.y, w.y, acc1[jj]);
            acc1[jj] = fmaf(xb.z, w.z, acc1[jj]);
            acc1[jj] = fmaf(xb.w, w.w, acc1[jj]);
        }
    }
#pragma unroll
    for (int jj = 0; jj < 4; ++jj) {
        float bj = bias[cg + jj];
        em[(rowbase + r0) * CC + cg + jj] = acc0[jj] + bj;
        em[(rowbase + r1) * CC + cg + jj] = acc1[jj] + bj;
    }
}

// ---------------------------------------------------------------------------
// Kernel 2: forward Viterbi scan. One wave per batch. Lane l: h=l>>5, j=l&31.
// alpha[j] distributed (mirrored across halves). Half h reduces i in [16h,16h+16)
// via ds_bpermute gathers; (val,idx) tournament reproduces jnp.argmax
// first-max tie-breaking exactly. bp packed 4 steps per dword.
// ---------------------------------------------------------------------------
__global__ __launch_bounds__(64) void viterbi_fwd(const float* __restrict__ em,
                                                  const float* __restrict__ T,
                                                  const float* __restrict__ startT,
                                                  const float* __restrict__ endT,
                                                  unsigned* __restrict__ bp,
                                                  float* __restrict__ out) {
    const int b = blockIdx.x;
    const int l = threadIdx.x;
    const int h = l >> 5;
    const int j = l & 31;
    const int h16 = h << 4;

    float Ti[16];
#pragma unroll
    for (int k = 0; k < 16; ++k) Ti[k] = T[(h16 + k) * CC + j];

    const float* eb = em + (long)b * SS * CC;
    float a = startT[j] + eb[j];       // t = 0

    float eq[8];
#pragma unroll
    for (int u = 0; u < 8; ++u) eq[u] = eb[(1 + u) * CC + j];

    unsigned bpw = 0;

    auto step = [&](float e, int t, int phase) {
        // gather alpha[i] for i = h16+k, add T[i][j]
        float s[16];
        int ai = __float_as_int(a);
#pragma unroll
        for (int k = 0; k < 16; ++k) {
            int av = __builtin_amdgcn_ds_bpermute((h16 + k) << 2, ai);
            s[k] = __int_as_float(av) + Ti[k];
        }
        // left-biased tournament (first max wins -> matches jnp.argmax)
        float bv[8]; int bi8[8];
#pragma unroll
        for (int p = 0; p < 8; ++p) {
            bool c = s[2 * p] >= s[2 * p + 1];
            bv[p] = c ? s[2 * p] : s[2 * p + 1];
            bi8[p] = c ? (2 * p) : (2 * p + 1);
        }
        float cv[4]; int ci[4];
#pragma unroll
        for (int p = 0; p < 4; ++p) {
            bool c = bv[2 * p] >= bv[2 * p + 1];
            cv[p] = c ? bv[2 * p] : bv[2 * p + 1];
            ci[p] = c ? bi8[2 * p] : bi8[2 * p + 1];
        }
        float dv[2]; int di[2];
#pragma unroll
        for (int p = 0; p < 2; ++p) {
            bool c = cv[2 * p] >= cv[2 * p + 1];
            dv[p] = c ? cv[2 * p] : cv[2 * p + 1];
            di[p] = c ? ci[2 * p] : ci[2 * p + 1];
        }
        bool cm = dv[0] >= dv[1];
        float mv = cm ? dv[0] : dv[1];
        int mi = (cm ? di[0] : di[1]) + h16;   // absolute i in [16h, 16h+16)

        // combine halves: prefer lower-i half (h=0) on ties
        float ov = __shfl_xor(mv, 32);
        int   oi = __shfl_xor(mi, 32);
        float v0 = h ? ov : mv, v1 = h ? mv : ov;
        int   i0 = h ? oi : mi, i1 = h ? mi : oi;
        bool c2 = v0 >= v1;
        float win = c2 ? v0 : v1;
        int bidx = c2 ? i0 : i1;

        a = win + e;

        int kk = t - 1;
        bpw |= (unsigned)bidx << (phase * 8);
        if (phase == 3) {
            if (h == 0) bp[((unsigned)(kk >> 2) * BB + b) * CC + j] = bpw;
            bpw = 0;
        }
    };

    int t = 1;
    for (int g = 0; g < 255; ++g) {
#pragma unroll
        for (int u = 0; u < 8; ++u) {
            float e = eq[u];
            step(e, t, (t - 1) & 3);
            int tn = t + 8;
            if (tn < 2048) eq[u] = eb[(long)tn * CC + j];
            ++t;
        }
    }
#pragma unroll
    for (int u = 0; u < 7; ++u) {      // t = 2041..2047
        step(eq[u], t, (t - 1) & 3);
        ++t;
    }
    // flush partial bp dword (kk = 2046, phase 2)
    if (h == 0) bp[(511u * BB + b) * CC + j] = bpw;

    // final: best_score + last tag (tie -> lowest j)
    float v = a + endT[j];
    int idx = j;
#pragma unroll
    for (int d = 1; d <= 16; d <<= 1) {
        float ovv = __shfl_xor(v, d);
        int   oii = __shfl_xor(idx, d);
        bool c = (ovv > v) || (ovv == v && oii < idx);
        v = c ? ovv : v;
        idx = c ? oii : idx;
    }
    if (l == 0) {
        out[b] = v;
        out[BB + (long)b * SS + (SS - 1)] = (float)idx;
    }
}

// ---------------------------------------------------------------------------
// Kernel 3: backtrack. One wave per batch; lane (l&31) holds dword j of the
// current 4-step bp row (prefetched, addresses tag-independent); the
// tag-dependent select is one uniform-address ds_bpermute per step.
// ---------------------------------------------------------------------------
__global__ __launch_bounds__(64) void viterbi_bt(const unsigned* __restrict__ bp,
                                                 float* __restrict__ out) {
    const int b = blockIdx.x;
    const int l = threadIdx.x;
    const int j = l & 31;
    float* path = out + BB + (long)b * SS;
    int tag = (int)path[SS - 1];       // written by viterbi_fwd

    unsigned cur = bp[(511u * BB + b) * CC + j];
    for (int sl = 511; sl >= 0; --sl) {
        unsigned nxt = 0;
        if (sl > 0) nxt = bp[((unsigned)(sl - 1) * BB + b) * CC + j];
#pragma unroll
        for (int p = 3; p >= 0; --p) {
            int k = sl * 4 + p;        // bp index 0..2046 (skip 2047)
            if (k > 2046) continue;
            unsigned row = (unsigned)__builtin_amdgcn_ds_bpermute(tag << 2, (int)cur);
            tag = (int)((row >> (p * 8)) & 0xFFu);
            if (l == 0) path[k] = (float)tag;
        }
        cur = nxt;
    }
}

// ---------------------------------------------------------------------------
extern "C" void kernel_launch(void* const* d_in, const int* in_sizes, int n_in,
                              void* d_out, int out_size, void* d_ws, size_t ws_size,
                              hipStream_t stream) {
    const float* X      = (const float*)d_in[0];
    const float* W      = (const float*)d_in[1];
    const float* bias   = (const float*)d_in[2];
    const float* T      = (const float*)d_in[3];
    const float* startT = (const float*)d_in[4];
    const float* endT   = (const float*)d_in[5];
    float* out = (float*)d_out;

    float*    em = (float*)d_ws;                                   // 16,777,216 B
    unsigned* bp = (unsigned*)((char*)d_ws + (size_t)BB * SS * CC * 4); // 4,194,304 B

    emis_kernel<<<(BB * SS) / 64, 256, 0, stream>>>(X, W, bias, em);
    viterbi_fwd<<<BB, 64, 0, stream>>>(em, T, startT, endT, bp, out);
    viterbi_bt<<<BB, 64, 0, stream>>>(bp, out);
}

// Round 3
// 753.461 us; speedup vs baseline: 1.3515x; 1.3515x over previous
//
#include <hip/hip_runtime.h>

#define BB 64
#define SS 2048
#define FF 256
#define CC 32

typedef unsigned u32x2 __attribute__((ext_vector_type(2)));

// Two-result permlane swaps. Builtins return {new_vdst, new_vsrc} and codegen
// guarantees distinct registers (the round-2 inline-asm version let clang
// coalesce the two tied "+v" operands into ONE register -> self-swap -> only
// 16 of 32 predecessor states were ever examined).
__device__ __forceinline__ void plswap16(int a_in, int& x, int& y) {
#if __has_builtin(__builtin_amdgcn_permlane16_swap)
    u32x2 r = __builtin_amdgcn_permlane16_swap((unsigned)a_in, (unsigned)a_in, false, false);
    x = (int)r[0]; y = (int)r[1];
#else
    int xx = a_in, yy;
    asm volatile("v_mov_b32 %0, %1" : "=v"(yy) : "v"(a_in));   // opaque copy -> distinct reg
    asm volatile("v_permlane16_swap_b32 %0, %1" : "+v"(xx), "+v"(yy));
    x = xx; y = yy;
#endif
}
__device__ __forceinline__ void plswap32(int a_in, int& x, int& y) {
#if __has_builtin(__builtin_amdgcn_permlane32_swap)
    u32x2 r = __builtin_amdgcn_permlane32_swap((unsigned)a_in, (unsigned)a_in, false, false);
    x = (int)r[0]; y = (int)r[1];
#else
    int xx = a_in, yy;
    asm volatile("v_mov_b32 %0, %1" : "=v"(yy) : "v"(a_in));
    asm volatile("v_permlane32_swap_b32 %0, %1" : "+v"(xx), "+v"(yy));
    x = xx; y = yy;
#endif
}

// ---------------------------------------------------------------------------
// Kernel 1: emissions[b,s,c] = sum_f X[b,s,f]*W[c,f] + bias[c]
// UNCHANGED (bit-exact, absmax 0.0 in round 1).
// ---------------------------------------------------------------------------
__global__ __launch_bounds__(256) void emis_kernel(const float* __restrict__ X,
                                                   const float* __restrict__ W,
                                                   const float* __restrict__ bias,
                                                   float* __restrict__ em) {
    __shared__ __align__(16) float xs[64 * 260];
    __shared__ __align__(16) float wsh[32 * 260];
    const int tid = threadIdx.x;
    const long rowbase = (long)blockIdx.x * 64;

    const float4* Xg = (const float4*)(X + rowbase * FF);
#pragma unroll
    for (int i = 0; i < 16; ++i) {
        int idx = tid + i * 256;
        int r = idx >> 6, c4 = idx & 63;
        *(float4*)&xs[r * 260 + c4 * 4] = Xg[idx];
    }
    const float4* Wg = (const float4*)W;
#pragma unroll
    for (int i = 0; i < 8; ++i) {
        int idx = tid + i * 256;
        int r = idx >> 6, c4 = idx & 63;
        *(float4*)&wsh[r * 260 + c4 * 4] = Wg[idx];
    }
    __syncthreads();

    const int rp = tid >> 3;
    const int cg = (tid & 7) * 4;
    const int r0 = rp * 2, r1 = rp * 2 + 1;
    float acc0[4] = {0.f, 0.f, 0.f, 0.f};
    float acc1[4] = {0.f, 0.f, 0.f, 0.f};

#pragma unroll 4
    for (int k = 0; k < 256; k += 4) {
        float4 xa = *(const float4*)&xs[r0 * 260 + k];
        float4 xb = *(const float4*)&xs[r1 * 260 + k];
#pragma unroll
        for (int jj = 0; jj < 4; ++jj) {
            float4 w = *(const float4*)&wsh[(cg + jj) * 260 + k];
            acc0[jj] = fmaf(xa.x, w.x, acc0[jj]);
            acc0[jj] = fmaf(xa.y, w.y, acc0[jj]);
            acc0[jj] = fmaf(xa.z, w.z, acc0[jj]);
            acc0[jj] = fmaf(xa.w, w.w, acc0[jj]);
            acc1[jj] = fmaf(xb.x, w.x, acc1[jj]);
            acc1[jj] = fmaf(xb.y, w.y, acc1[jj]);
            acc1[jj] = fmaf(xb.z, w.z, acc1[jj]);
            acc1[jj] = fmaf(xb.w, w.w, acc1[jj]);
        }
    }
#pragma unroll
    for (int jj = 0; jj < 4; ++jj) {
        float bj = bias[cg + jj];
        em[(rowbase + r0) * CC + cg + jj] = acc0[jj] + bj;
        em[(rowbase + r1) * CC + cg + jj] = acc1[jj] + bj;
    }
}

// ---------------------------------------------------------------------------
// Kernel 2: forward Viterbi scan — all-VALU inner loop.
// Lane l holds a[l&31] (mirrored). Per step: permlane16_swap replicates the
// two alpha-halves into every 16-lane row; 15 DPP row_ror enumerate the 16
// candidates; fmaxf tree + eq/min-index tree = exact jnp.argmax semantics;
// permlane32_swap combines halves. Lane maps are probe-derived.
// ---------------------------------------------------------------------------
#define ROT1(d, s, K) d = __builtin_amdgcn_update_dpp(s, s, 0x120 + K, 0xF, 0xF, false)
#define ROTALL(arr, s) \
    arr[0] = s;        \
    ROT1(arr[1], s, 1);  ROT1(arr[2], s, 2);  ROT1(arr[3], s, 3);  \
    ROT1(arr[4], s, 4);  ROT1(arr[5], s, 5);  ROT1(arr[6], s, 6);  \
    ROT1(arr[7], s, 7);  ROT1(arr[8], s, 8);  ROT1(arr[9], s, 9);  \
    ROT1(arr[10], s, 10); ROT1(arr[11], s, 11); ROT1(arr[12], s, 12); \
    ROT1(arr[13], s, 13); ROT1(arr[14], s, 14); ROT1(arr[15], s, 15)

__device__ __forceinline__ int imin_(int a, int b) { return a < b ? a : b; }

__global__ __launch_bounds__(64) void viterbi_fwd(const float* __restrict__ em,
                                                  const float* __restrict__ T,
                                                  const float* __restrict__ startT,
                                                  const float* __restrict__ endT,
                                                  unsigned* __restrict__ bp,
                                                  float* __restrict__ out) {
    const int b = blockIdx.x;
    const int l = threadIdx.x;
    const int j = l & 31;
    const int h = l >> 5;

    // probe permlane16_swap: which result holds alpha-half h at this lane?
    int p0, p1;
    plswap16(j, p0, p1);
    const bool c16 = (((p0 >> 4) & 1) == h);
    const int pm = c16 ? p0 : p1;
    int mk[16];
    ROTALL(mk, pm);                    // mk[k] = abs alpha-index delivered by rot k

    // probe permlane32_swap: which result holds partner lane l^32?
    int q0, q1;
    plswap32(l, q0, q1);
    const bool pick0 = (q0 == (l ^ 32));

    float Ti[16];
#pragma unroll
    for (int k = 0; k < 16; ++k) Ti[k] = T[mk[k] * CC + j];

    const float* eb = em + (long)b * SS * CC;
    float a = startT[j] + eb[j];       // t = 0

    float eq[8];
#pragma unroll
    for (int u = 0; u < 8; ++u) eq[u] = eb[(1 + u) * CC + j];

    unsigned bpw = 0;

    auto step = [&](float e, int t, int phase) {
        int x, y;
        plswap16(__float_as_int(a), x, y);
        int base = c16 ? x : y;
        int rot[16];
        ROTALL(rot, base);
        float s[16];
#pragma unroll
        for (int k = 0; k < 16; ++k) s[k] = __int_as_float(rot[k]) + Ti[k];

        float m0 = fmaxf(s[0], s[1]),  m1 = fmaxf(s[2], s[3]);
        float m2 = fmaxf(s[4], s[5]),  m3 = fmaxf(s[6], s[7]);
        float m4 = fmaxf(s[8], s[9]),  m5 = fmaxf(s[10], s[11]);
        float m6 = fmaxf(s[12], s[13]), m7 = fmaxf(s[14], s[15]);
        float n0 = fmaxf(m0, m1), n1 = fmaxf(m2, m3);
        float n2 = fmaxf(m4, m5), n3 = fmaxf(m6, m7);
        float mv = fmaxf(fmaxf(n0, n1), fmaxf(n2, n3));

        int c0 = (s[0] == mv) ? mk[0] : 63,   c1 = (s[1] == mv) ? mk[1] : 63;
        int c2 = (s[2] == mv) ? mk[2] : 63,   c3 = (s[3] == mv) ? mk[3] : 63;
        int c4 = (s[4] == mv) ? mk[4] : 63,   c5 = (s[5] == mv) ? mk[5] : 63;
        int c6 = (s[6] == mv) ? mk[6] : 63,   c7 = (s[7] == mv) ? mk[7] : 63;
        int c8 = (s[8] == mv) ? mk[8] : 63,   c9 = (s[9] == mv) ? mk[9] : 63;
        int c10 = (s[10] == mv) ? mk[10] : 63, c11 = (s[11] == mv) ? mk[11] : 63;
        int c12 = (s[12] == mv) ? mk[12] : 63, c13 = (s[13] == mv) ? mk[13] : 63;
        int c14 = (s[14] == mv) ? mk[14] : 63, c15 = (s[15] == mv) ? mk[15] : 63;
        int e0 = imin_(c0, c1), e1 = imin_(c2, c3), e2 = imin_(c4, c5), e3 = imin_(c6, c7);
        int e4 = imin_(c8, c9), e5 = imin_(c10, c11), e6 = imin_(c12, c13), e7 = imin_(c14, c15);
        int f0 = imin_(e0, e1), f1 = imin_(e2, e3), f2 = imin_(e4, e5), f3 = imin_(e6, e7);
        int mi = imin_(imin_(f0, f1), imin_(f2, f3));

        int xm, ym;
        plswap32(__float_as_int(mv), xm, ym);
        float ov = __int_as_float(pick0 ? xm : ym);
        int xi, yi;
        plswap32(mi, xi, yi);
        int omi = pick0 ? xi : yi;
        bool take = (ov > mv) || (ov == mv && omi < mi);
        float wv = take ? ov : mv;
        int wi = take ? omi : mi;

        a = wv + e;

        int kk = t - 1;
        bpw |= (unsigned)wi << (phase * 8);
        if (phase == 3) {
            if (h == 0) bp[((unsigned)(kk >> 2) * BB + b) * CC + j] = bpw;
            bpw = 0;
        }
    };

    int t = 1;
    for (int g = 0; g < 255; ++g) {
#pragma unroll
        for (int u = 0; u < 8; ++u) {
            float e = eq[u];
            step(e, t, (t - 1) & 3);
            int tn = t + 8;
            if (tn < 2048) eq[u] = eb[(long)tn * CC + j];
            ++t;
        }
    }
#pragma unroll
    for (int u = 0; u < 7; ++u) {      // t = 2041..2047
        step(eq[u], t, (t - 1) & 3);
        ++t;
    }
    // slot 511: phases 0..2 real + IDENTITY byte in phase 3 (uniform 64-walks)
    bpw |= (unsigned)j << 24;
    if (h == 0) bp[(511u * BB + b) * CC + j] = bpw;

    float v = a + endT[j];
    int idx = j;
#pragma unroll
    for (int d = 1; d <= 16; d <<= 1) {
        float ovv = __shfl_xor(v, d);
        int   oii = __shfl_xor(idx, d);
        bool c = (ovv > v) || (ovv == v && oii < idx);
        v = c ? ovv : v;
        idx = c ? oii : idx;
    }
    if (l == 0) {
        out[b] = v;
        out[BB + (long)b * SS + (SS - 1)] = (float)idx;
    }
}

// ---------------------------------------------------------------------------
// Backtrack as a function-composition scan over 32 chunks of 64 steps.
// ---------------------------------------------------------------------------
__global__ __launch_bounds__(64) void bt_compose(const unsigned* __restrict__ bp,
                                                 unsigned char* __restrict__ G) {
    const int l = threadIdx.x, j = l & 31, hh = l >> 5;
    const int b = blockIdx.x >> 4;
    const int k = ((blockIdx.x & 15) << 1) | hh;
    const int lanebase = l & 32;

    unsigned sr[16];
#pragma unroll
    for (int p = 0; p < 16; ++p) sr[p] = bp[((unsigned)(16 * k + p) * BB + b) * CC + j];

    int g = j;
#pragma unroll
    for (int rel = 63; rel >= 0; --rel) {
        unsigned dw = (unsigned)__builtin_amdgcn_ds_bpermute((g | lanebase) << 2,
                                                             (int)sr[rel >> 2]);
        g = (int)((dw >> ((rel & 3) * 8)) & 31u);
    }
    G[(b * 32 + k) * 32 + j] = (unsigned char)g;
}

__global__ __launch_bounds__(64) void bt_scan(const unsigned char* __restrict__ G,
                                              const float* __restrict__ out,
                                              int* __restrict__ tagB) {
    __shared__ unsigned char Gs[64 * 32 * 32];
    const int l = threadIdx.x;
    const float4* Gg = (const float4*)G;
    float4* Gls = (float4*)Gs;
#pragma unroll
    for (int i = 0; i < 64; ++i) Gls[l + i * 64] = Gg[l + i * 64];
    __syncthreads();

    const int b = l;
    int cur = (int)out[BB + (long)b * SS + (SS - 1)];
    for (int k = 31; k >= 0; --k) {
        cur = Gs[(b * 32 + k) * 32 + cur];
        tagB[b * 32 + k] = cur;
    }
}

__global__ __launch_bounds__(64) void bt_emit(const unsigned* __restrict__ bp,
                                              const int* __restrict__ tagB,
                                              float* __restrict__ out) {
    const int l = threadIdx.x;
    const int b = blockIdx.x >> 5;
    const int k = blockIdx.x & 31;

    unsigned sr[16];
#pragma unroll
    for (int p = 0; p < 16; ++p) sr[p] = bp[((unsigned)(16 * k + p) * BB + b) * CC + (l & 31)];

    int start = (k == 31) ? (int)out[BB + (long)b * SS + (SS - 1)]
                          : tagB[b * 32 + k + 1];
    int g = start, cap = start;
#pragma unroll
    for (int rel = 63; rel >= 0; --rel) {
        unsigned dw = (unsigned)__builtin_amdgcn_ds_bpermute((g | (l & 32)) << 2,
                                                             (int)sr[rel >> 2]);
        g = (int)((dw >> ((rel & 3) * 8)) & 31u);
        cap = (l == rel) ? g : cap;
    }
    out[BB + (long)b * SS + k * 64 + l] = (float)cap;
}

// ---------------------------------------------------------------------------
extern "C" void kernel_launch(void* const* d_in, const int* in_sizes, int n_in,
                              void* d_out, int out_size, void* d_ws, size_t ws_size,
                              hipStream_t stream) {
    const float* X      = (const float*)d_in[0];
    const float* W      = (const float*)d_in[1];
    const float* bias   = (const float*)d_in[2];
    const float* T      = (const float*)d_in[3];
    const float* startT = (const float*)d_in[4];
    const float* endT   = (const float*)d_in[5];
    float* out = (float*)d_out;

    float*    em = (float*)d_ws;                                        // 16 MB
    unsigned* bp = (unsigned*)((char*)d_ws + (size_t)BB * SS * CC * 4); // 4 MB
    unsigned char* G    = (unsigned char*)d_ws;                         // reuse em head
    int*           tagB = (int*)((char*)d_ws + 65536);

    emis_kernel<<<(BB * SS) / 64, 256, 0, stream>>>(X, W, bias, em);
    viterbi_fwd<<<BB, 64, 0, stream>>>(em, T, startT, endT, bp, out);
    bt_compose<<<BB * 16, 64, 0, stream>>>(bp, G);
    bt_scan<<<1, 64, 0, stream>>>(G, out, tagB);
    bt_emit<<<BB * 32, 64, 0, stream>>>(bp, tagB, out);
}